// Round 2
// baseline (252.718 us; speedup 1.0000x reference)
//
#include <hip/hip_runtime.h>

#define DI __device__ __forceinline__

using f32x4  = __attribute__((ext_vector_type(4))) float;
using bf16x8 = __attribute__((ext_vector_type(8))) short;
using bf16x4 = __attribute__((ext_vector_type(4))) short;
using u32x2  = __attribute__((ext_vector_type(2))) unsigned int;

DI unsigned short f2bf(float f) {
    unsigned int u = __float_as_uint(f);
    unsigned int r = u + 0x7FFFu + ((u >> 16) & 1u);
    return (unsigned short)(r >> 16);
}

// ---- problem constants ----
constexpr int N_SEQ = 8192;
constexpr int QH    = 32;
constexpr int KH    = 2;
constexpr int D     = 128;
constexpr int M_CMP = 511;
constexpr int MP    = 512;

// ============ Stage 1: block compress (unchanged, verified) ============
__global__ __launch_bounds__(256)
void compress_kernel(const float* __restrict__ kin, const float* __restrict__ vin,
                     const float* __restrict__ w_key, const float* __restrict__ pe_key,
                     const float* __restrict__ w_val, const float* __restrict__ pe_val,
                     float* __restrict__ ck_out,
                     unsigned short* __restrict__ ckb,
                     unsigned short* __restrict__ cvbT)
{
    const int m  = blockIdx.x;
    const int t  = threadIdx.x;
    const int hh = t >> 7;
    const int d  = t & 127;
    float acck = 0.f, accv = 0.f;
    if (m < M_CMP) {
        #pragma unroll
        for (int k = 0; k < 32; ++k) {
            float xk = kin[((m*16 + k)*KH + hh)*D + d];
            float xv = vin[((m*16 + k)*KH + hh)*D + d];
            acck += (xk + pe_key[k*D + d]) * w_key[k];
            accv += (xv + pe_val[k*D + d]) * w_val[k];
        }
        acck *= (1.f/32.f);
        accv *= (1.f/32.f);
        ck_out[(m*KH + hh)*D + d] = acck;
    }
    ckb[(hh*MP + m)*D + d]  = f2bf(acck);
    cvbT[(hh*D + d)*MP + m] = f2bf(accv);
}

// ============ Stage 2: barrier-free flash attention ============
// 256 threads = 4 waves; wave owns 2 consecutive n. No LDS, no barriers.
// Swapped QK^T: S^T[m][g] = mfma(A=ck, B=q). C layout: col=lane&15 (=g),
// row=hi*4+j (=m_local). P^T then feeds 16x16x16 PV B-frags directly.
__global__ __launch_bounds__(256)
void attn_kernel(const float* __restrict__ q,
                 const unsigned short* __restrict__ ckb,
                 const unsigned short* __restrict__ cvbT,
                 float* __restrict__ o,
                 float* __restrict__ lse)
{
    const int h    = blockIdx.y;
    const int t    = threadIdx.x;
    const int wid  = t >> 6;
    const int lane = t & 63;
    const int col  = lane & 15;
    const int hi   = lane >> 4;
    const int nb   = (blockIdx.x << 3) + (wid << 1);

    const float sm_scale = 0.08838834764831845f;
    const float NEG_INF  = -__builtin_inff();

    int mcnt[2];
    bf16x8 qf[2][4];
    #pragma unroll
    for (int rt = 0; rt < 2; ++rt) {
        const int n = nb + rt;
        mcnt[rt] = (n >= 31) ? (((n - 31) >> 4) + 1) : 0;
        // B-frag: B[k=d][col=g] = q[n][h*16+col][d], k = hi*8 + i (pre-scaled)
        const float* qp = q + ((size_t)n*QH + (h << 4) + col)*D + (hi << 3);
        #pragma unroll
        for (int kc = 0; kc < 4; ++kc) {
            float4 a = *(const float4*)(qp + kc*32);
            float4 b = *(const float4*)(qp + kc*32 + 4);
            bf16x8 f;
            f[0] = (short)f2bf(a.x*sm_scale); f[1] = (short)f2bf(a.y*sm_scale);
            f[2] = (short)f2bf(a.z*sm_scale); f[3] = (short)f2bf(a.w*sm_scale);
            f[4] = (short)f2bf(b.x*sm_scale); f[5] = (short)f2bf(b.y*sm_scale);
            f[6] = (short)f2bf(b.z*sm_scale); f[7] = (short)f2bf(b.w*sm_scale);
            qf[rt][kc] = f;
        }
    }

    f32x4 oacc[2][8];
    #pragma unroll
    for (int rt = 0; rt < 2; ++rt)
        #pragma unroll
        for (int dt = 0; dt < 8; ++dt)
            oacc[rt][dt] = (f32x4){0.f, 0.f, 0.f, 0.f};
    float rmax[2] = {-3e38f, -3e38f};
    float rsum[2] = {0.f, 0.f};

    const int nch = (mcnt[1] + 31) >> 5;   // mcnt[1] >= mcnt[0]

    // A-frag base for QK: ck[m = m0+mt*16+col][d = kc*32+hi*8]
    const unsigned short* ckbase = ckb + (((size_t)h*MP + col) << 7) + (hi << 3);
    // A-frag base for PV: cvT[d = dt*16+col][m = m0+mt*16+hi*4]
    const unsigned short* cvbase = cvbT + ((size_t)h*D + col)*MP + (hi << 2);

    for (int c = 0; c < nch; ++c) {
        const int m0 = c << 5;
        const unsigned short* ckp = ckbase + ((size_t)m0 << 7);

        f32x4 s[2][2];
        s[0][0] = (f32x4){0,0,0,0}; s[0][1] = (f32x4){0,0,0,0};
        s[1][0] = (f32x4){0,0,0,0}; s[1][1] = (f32x4){0,0,0,0};
        #pragma unroll
        for (int kc = 0; kc < 4; ++kc) {
            bf16x8 ca = *(const bf16x8*)(ckp + kc*32);           // mt=0 rows
            bf16x8 cb = *(const bf16x8*)(ckp + 2048 + kc*32);    // mt=1 rows (+16*128)
            s[0][0] = __builtin_amdgcn_mfma_f32_16x16x32_bf16(ca, qf[0][kc], s[0][0], 0, 0, 0);
            s[1][0] = __builtin_amdgcn_mfma_f32_16x16x32_bf16(ca, qf[1][kc], s[1][0], 0, 0, 0);
            s[0][1] = __builtin_amdgcn_mfma_f32_16x16x32_bf16(cb, qf[0][kc], s[0][1], 0, 0, 0);
            s[1][1] = __builtin_amdgcn_mfma_f32_16x16x32_bf16(cb, qf[1][kc], s[1][1], 0, 0, 0);
        }

        unsigned int pbw[2][4];   // [rt][mt*2 + reg] packed bf16 P^T B-frags
        #pragma unroll
        for (int rt = 0; rt < 2; ++rt) {
            const int lim = mcnt[rt] - m0;     // wave-uniform
            const int mb  = hi << 2;
            float sv[8];
            #pragma unroll
            for (int mt = 0; mt < 2; ++mt)
                #pragma unroll
                for (int j = 0; j < 4; ++j) {
                    float x = s[rt][mt][j];
                    sv[mt*4 + j] = ((mt << 4) + mb + j < lim) ? x : NEG_INF;
                }
            float pm = fmaxf(fmaxf(fmaxf(sv[0],sv[1]), fmaxf(sv[2],sv[3])),
                             fmaxf(fmaxf(sv[4],sv[5]), fmaxf(sv[6],sv[7])));
            if (!__all(pm <= rmax[rt] + 8.0f)) {
                float tm = pm;
                tm = fmaxf(tm, __shfl_xor(tm, 16));
                tm = fmaxf(tm, __shfl_xor(tm, 32));
                float nm = fmaxf(rmax[rt], tm);
                float sc = __expf(rmax[rt] - nm);
                rsum[rt] *= sc;
                #pragma unroll
                for (int dt = 0; dt < 8; ++dt) {
                    oacc[rt][dt][0] *= sc; oacc[rt][dt][1] *= sc;
                    oacc[rt][dt][2] *= sc; oacc[rt][dt][3] *= sc;
                }
                rmax[rt] = nm;
            }
            float p[8], lsum = 0.f;
            #pragma unroll
            for (int i = 0; i < 8; ++i) {
                p[i] = __expf(sv[i] - rmax[rt]);
                lsum += p[i];
            }
            rsum[rt] += lsum;
            unsigned int u0, u1, u2, u3;
            asm("v_cvt_pk_bf16_f32 %0, %1, %2" : "=v"(u0) : "v"(p[0]), "v"(p[1]));
            asm("v_cvt_pk_bf16_f32 %0, %1, %2" : "=v"(u1) : "v"(p[2]), "v"(p[3]));
            asm("v_cvt_pk_bf16_f32 %0, %1, %2" : "=v"(u2) : "v"(p[4]), "v"(p[5]));
            asm("v_cvt_pk_bf16_f32 %0, %1, %2" : "=v"(u3) : "v"(p[6]), "v"(p[7]));
            pbw[rt][0] = u0; pbw[rt][1] = u1; pbw[rt][2] = u2; pbw[rt][3] = u3;
        }

        // ---- PV: O^T[d][g] += cvT * P^T via 16x16x16 MFMA ----
        #pragma unroll
        for (int dt = 0; dt < 8; ++dt) {
            const unsigned short* cvp = cvbase + (dt << 13) + m0;  // dt*16*512
            bf16x4 a0 = *(const bf16x4*)(cvp);
            bf16x4 a1 = *(const bf16x4*)(cvp + 16);
            #pragma unroll
            for (int rt = 0; rt < 2; ++rt) {
                u32x2 b0 = {pbw[rt][0], pbw[rt][1]};
                u32x2 b1 = {pbw[rt][2], pbw[rt][3]};
                asm("v_mfma_f32_16x16x16_bf16 %0, %1, %2, %0"
                    : "+v"(oacc[rt][dt]) : "v"(a0), "v"(b0));
                asm("v_mfma_f32_16x16x16_bf16 %0, %1, %2, %0"
                    : "+v"(oacc[rt][dt]) : "v"(a1), "v"(b1));
            }
        }
    }

    // ---- epilogue ----
    #pragma unroll
    for (int rt = 0; rt < 2; ++rt) {
        const int n = nb + rt;
        float r = rsum[rt];
        r += __shfl_xor(r, 16);
        r += __shfl_xor(r, 32);
        const bool valid = mcnt[rt] > 0;
        const float inv = valid ? (1.0f / r) : 0.0f;
        float* op = o + ((size_t)n*QH + (h << 4) + col)*D + (hi << 2);
        #pragma unroll
        for (int dt = 0; dt < 8; ++dt) {
            f32x4 w = oacc[rt][dt];
            w[0] *= inv; w[1] *= inv; w[2] *= inv; w[3] *= inv;
            *(f32x4*)(op + dt*16) = w;
        }
        if (lane < 16) {
            float lv = valid ? (rmax[rt] + __logf(r)) : 0.0f;
            lse[((size_t)(h << 4) + col)*N_SEQ + n] = lv;
        }
    }
}

extern "C" void kernel_launch(void* const* d_in, const int* in_sizes, int n_in,
                              void* d_out, int out_size, void* d_ws, size_t ws_size,
                              hipStream_t stream)
{
    const float* q      = (const float*)d_in[0];
    const float* k      = (const float*)d_in[1];
    const float* v      = (const float*)d_in[2];
    const float* w_key  = (const float*)d_in[3];
    const float* pe_key = (const float*)d_in[4];
    const float* w_val  = (const float*)d_in[5];
    const float* pe_val = (const float*)d_in[6];

    float* o   = (float*)d_out;                    // (1, 8192, 32, 128)
    float* lse = o + (size_t)N_SEQ * QH * D;       // (1, 32, 8192)
    float* ck  = lse + (size_t)QH * N_SEQ;         // (1, 511, 2, 128)

    unsigned short* ckb  = (unsigned short*)d_ws;  // [KH][512][128] bf16
    unsigned short* cvbT = ckb + (size_t)KH*MP*D;  // [KH][128][512] bf16

    compress_kernel<<<dim3(MP), dim3(256), 0, stream>>>(
        k, v, w_key, pe_key, w_val, pe_val, ck, ckb, cvbT);

    attn_kernel<<<dim3(N_SEQ/8, KH), dim3(256), 0, stream>>>(
        q, ckb, cvbT, o, lse);
}

// Round 4
// 243.894 us; speedup vs baseline: 1.0362x; 1.0362x over previous
//
#include <hip/hip_runtime.h>

#define DI __device__ __forceinline__

using f32x4  = __attribute__((ext_vector_type(4))) float;
using bf16x8 = __attribute__((ext_vector_type(8))) short;
using bf16x4 = __attribute__((ext_vector_type(4))) short;
using u32x2  = __attribute__((ext_vector_type(2))) unsigned int;

DI unsigned short f2bf(float f) {
    unsigned int u = __float_as_uint(f);
    unsigned int r = u + 0x7FFFu + ((u >> 16) & 1u);
    return (unsigned short)(r >> 16);
}

// ---- problem constants ----
constexpr int N_SEQ = 8192;
constexpr int QH    = 32;
constexpr int KH    = 2;
constexpr int D     = 128;
constexpr int M_CMP = 511;
constexpr int MP    = 512;

// ============ Stage 1: block compress ============
// cvbT stores m within each 32-chunk in widx-permuted order so the PV
// A-fragment (m = mt*16 + hi*4 + j, both mt) is ONE contiguous 16B load:
// widx = hi*8 + mt*4 + j.
__global__ __launch_bounds__(256)
void compress_kernel(const float* __restrict__ kin, const float* __restrict__ vin,
                     const float* __restrict__ w_key, const float* __restrict__ pe_key,
                     const float* __restrict__ w_val, const float* __restrict__ pe_val,
                     float* __restrict__ ck_out,
                     unsigned short* __restrict__ ckb,
                     unsigned short* __restrict__ cvbT)
{
    const int m  = blockIdx.x;
    const int t  = threadIdx.x;
    const int hh = t >> 7;
    const int d  = t & 127;
    float acck = 0.f, accv = 0.f;
    if (m < M_CMP) {
        #pragma unroll
        for (int k = 0; k < 32; ++k) {
            float xk = kin[((m*16 + k)*KH + hh)*D + d];
            float xv = vin[((m*16 + k)*KH + hh)*D + d];
            acck += (xk + pe_key[k*D + d]) * w_key[k];
            accv += (xv + pe_val[k*D + d]) * w_val[k];
        }
        acck *= (1.f/32.f);
        accv *= (1.f/32.f);
        ck_out[(m*KH + hh)*D + d] = acck;
    }
    ckb[(hh*MP + m)*D + d] = f2bf(acck);
    const int ml   = m & 31;                                   // mt*16+hi*4+j
    const int widx = (((ml >> 2) & 3) << 3) + (((ml >> 4) & 1) << 2) + (ml & 3);
    cvbT[(hh*D + d)*MP + (m & ~31) + widx] = f2bf(accv);
}

// ============ Stage 2: balanced, register-double-buffered attention ============
// 256 threads = 4 waves. Wave owns rows j and 8191-j (mirror pairing ->
// every wave has ~equal total work). KV chunk (ck 8x16B + cv 8x16B) is
// prefetched into a second register buffer one chunk ahead.
__global__ __launch_bounds__(256)
void attn_kernel(const float* __restrict__ q,
                 const unsigned short* __restrict__ ckb,
                 const unsigned short* __restrict__ cvbT,
                 float* __restrict__ o,
                 float* __restrict__ lse)
{
    const int h    = blockIdx.y;
    const int t    = threadIdx.x;
    const int wid  = t >> 6;
    const int lane = t & 63;
    const int col  = lane & 15;
    const int hi   = lane >> 4;
    const int j    = (blockIdx.x << 2) + wid;      // 0..4095

    const int n0r = j;                // short row
    const int n1r = N_SEQ - 1 - j;    // long row (>= 4096)
    const int mcnt0 = (n0r >= 31) ? (((n0r - 31) >> 4) + 1) : 0;
    const int mcnt1 = ((n1r - 31) >> 4) + 1;
    const int nch   = (mcnt1 + 31) >> 5;           // 8..16

    const float sm_scale = 0.08838834764831845f;
    const float NEG_INF  = -__builtin_inff();

    // ---- Q fragments (B-frag of swapped QK^T): B[k=d][col=g] ----
    bf16x8 qf0[4], qf1[4];
    {
        const float* qp0 = q + ((size_t)n0r*QH + (h << 4) + col)*D + (hi << 3);
        const float* qp1 = q + ((size_t)n1r*QH + (h << 4) + col)*D + (hi << 3);
        #pragma unroll
        for (int kc = 0; kc < 4; ++kc) {
            float4 a0 = *(const float4*)(qp0 + kc*32);
            float4 b0 = *(const float4*)(qp0 + kc*32 + 4);
            float4 a1 = *(const float4*)(qp1 + kc*32);
            float4 b1 = *(const float4*)(qp1 + kc*32 + 4);
            bf16x8 f0, f1;
            f0[0]=(short)f2bf(a0.x*sm_scale); f0[1]=(short)f2bf(a0.y*sm_scale);
            f0[2]=(short)f2bf(a0.z*sm_scale); f0[3]=(short)f2bf(a0.w*sm_scale);
            f0[4]=(short)f2bf(b0.x*sm_scale); f0[5]=(short)f2bf(b0.y*sm_scale);
            f0[6]=(short)f2bf(b0.z*sm_scale); f0[7]=(short)f2bf(b0.w*sm_scale);
            f1[0]=(short)f2bf(a1.x*sm_scale); f1[1]=(short)f2bf(a1.y*sm_scale);
            f1[2]=(short)f2bf(a1.z*sm_scale); f1[3]=(short)f2bf(a1.w*sm_scale);
            f1[4]=(short)f2bf(b1.x*sm_scale); f1[5]=(short)f2bf(b1.y*sm_scale);
            f1[6]=(short)f2bf(b1.z*sm_scale); f1[7]=(short)f2bf(b1.w*sm_scale);
            qf0[kc] = f0; qf1[kc] = f1;
        }
    }

    f32x4 oacc0[8], oacc1[8];
    #pragma unroll
    for (int dt = 0; dt < 8; ++dt) {
        oacc0[dt] = (f32x4){0.f,0.f,0.f,0.f};
        oacc1[dt] = (f32x4){0.f,0.f,0.f,0.f};
    }
    float rmax0 = -3e38f, rmax1 = -3e38f, rsum0 = 0.f, rsum1 = 0.f;

    // QK A-frag: ck[m = m0 + mt*16 + col][d = kc*32 + hi*8]
    const unsigned short* ckbase = ckb + (((size_t)h*MP + col) << 7) + (hi << 3);
    // PV A-frag: cvT2[d = dt*16 + col][chunk m0 + widx hi*8 .. hi*8+7]
    const unsigned short* cvbase = cvbT + ((size_t)h*D + col)*MP + (hi << 3);

    bf16x8 ckA[8], cvA[8], ckB[8], cvB[8];

    auto LOAD = [&](bf16x8* ckr, bf16x8* cvr, int m0) {
        const unsigned short* ckp = ckbase + ((size_t)m0 << 7);
        #pragma unroll
        for (int kc = 0; kc < 4; ++kc) {
            ckr[kc]     = *(const bf16x8*)(ckp + kc*32);
            ckr[4 + kc] = *(const bf16x8*)(ckp + 2048 + kc*32);
        }
        const unsigned short* cvp = cvbase + m0;
        #pragma unroll
        for (int dt = 0; dt < 8; ++dt)
            cvr[dt] = *(const bf16x8*)(cvp + (dt << 13));
    };

    // softmax for one row: sa = mt0 scores, sb = mt1 scores
    auto SMAX = [&](f32x4 sa, f32x4 sb, int lim, float& rm, float& rs,
                    f32x4* oaccr, unsigned int* pw) {
        const int mb = hi << 2;
        float sv[8];
        #pragma unroll
        for (int jj = 0; jj < 4; ++jj) {
            sv[jj]     = (mb + jj      < lim) ? sa[jj] : NEG_INF;
            sv[4 + jj] = (mb + jj + 16 < lim) ? sb[jj] : NEG_INF;
        }
        float pm = fmaxf(fmaxf(fmaxf(sv[0],sv[1]), fmaxf(sv[2],sv[3])),
                         fmaxf(fmaxf(sv[4],sv[5]), fmaxf(sv[6],sv[7])));
        if (!__all(pm <= rm + 8.0f)) {
            float tm = pm;
            tm = fmaxf(tm, __shfl_xor(tm, 16));
            tm = fmaxf(tm, __shfl_xor(tm, 32));
            float nm = fmaxf(rm, tm);
            float sc = __expf(rm - nm);
            rs *= sc;
            #pragma unroll
            for (int dt = 0; dt < 8; ++dt) {
                oaccr[dt][0] *= sc; oaccr[dt][1] *= sc;
                oaccr[dt][2] *= sc; oaccr[dt][3] *= sc;
            }
            rm = nm;
        }
        float p[8], lsum = 0.f;
        #pragma unroll
        for (int i = 0; i < 8; ++i) { p[i] = __expf(sv[i] - rm); lsum += p[i]; }
        rs += lsum;
        asm("v_cvt_pk_bf16_f32 %0, %1, %2" : "=v"(pw[0]) : "v"(p[0]), "v"(p[1]));
        asm("v_cvt_pk_bf16_f32 %0, %1, %2" : "=v"(pw[1]) : "v"(p[2]), "v"(p[3]));
        asm("v_cvt_pk_bf16_f32 %0, %1, %2" : "=v"(pw[2]) : "v"(p[4]), "v"(p[5]));
        asm("v_cvt_pk_bf16_f32 %0, %1, %2" : "=v"(pw[3]) : "v"(p[6]), "v"(p[7]));
    };

    auto PROCESS = [&](const bf16x8* ckr, const bf16x8* cvr, int c) {
        const int m0   = c << 5;
        const bool act0 = (m0 < mcnt0);          // wave-uniform

        // ---- QK^T long row (always active) ----
        f32x4 s10 = (f32x4){0,0,0,0}, s11 = (f32x4){0,0,0,0};
        #pragma unroll
        for (int kc = 0; kc < 4; ++kc) {
            s10 = __builtin_amdgcn_mfma_f32_16x16x32_bf16(ckr[kc],     qf1[kc], s10, 0, 0, 0);
            s11 = __builtin_amdgcn_mfma_f32_16x16x32_bf16(ckr[4 + kc], qf1[kc], s11, 0, 0, 0);
        }
        unsigned int pw1[4];
        SMAX(s10, s11, mcnt1 - m0, rmax1, rsum1, oacc1, pw1);

        unsigned int pw0[4];
        if (act0) {
            f32x4 s00 = (f32x4){0,0,0,0}, s01 = (f32x4){0,0,0,0};
            #pragma unroll
            for (int kc = 0; kc < 4; ++kc) {
                s00 = __builtin_amdgcn_mfma_f32_16x16x32_bf16(ckr[kc],     qf0[kc], s00, 0, 0, 0);
                s01 = __builtin_amdgcn_mfma_f32_16x16x32_bf16(ckr[4 + kc], qf0[kc], s01, 0, 0, 0);
            }
            SMAX(s00, s01, mcnt0 - m0, rmax0, rsum0, oacc0, pw0);
        }

        // ---- PV long row ----
        {
            u32x2 b0 = {pw1[0], pw1[1]}, b1 = {pw1[2], pw1[3]};
            #pragma unroll
            for (int dt = 0; dt < 8; ++dt) {
                bf16x4 a0 = __builtin_shufflevector(cvr[dt], cvr[dt], 0,1,2,3);
                bf16x4 a1 = __builtin_shufflevector(cvr[dt], cvr[dt], 4,5,6,7);
                asm("v_mfma_f32_16x16x16_bf16 %0, %1, %2, %0"
                    : "+v"(oacc1[dt]) : "v"(a0), "v"(b0));
                asm("v_mfma_f32_16x16x16_bf16 %0, %1, %2, %0"
                    : "+v"(oacc1[dt]) : "v"(a1), "v"(b1));
            }
        }
        // ---- PV short row ----
        if (act0) {
            u32x2 b0 = {pw0[0], pw0[1]}, b1 = {pw0[2], pw0[3]};
            #pragma unroll
            for (int dt = 0; dt < 8; ++dt) {
                bf16x4 a0 = __builtin_shufflevector(cvr[dt], cvr[dt], 0,1,2,3);
                bf16x4 a1 = __builtin_shufflevector(cvr[dt], cvr[dt], 4,5,6,7);
                asm("v_mfma_f32_16x16x16_bf16 %0, %1, %2, %0"
                    : "+v"(oacc0[dt]) : "v"(a0), "v"(b0));
                asm("v_mfma_f32_16x16x16_bf16 %0, %1, %2, %0"
                    : "+v"(oacc0[dt]) : "v"(a1), "v"(b1));
            }
        }
    };

    // ---- software-pipelined chunk loop (A/B register double-buffer) ----
    LOAD(ckA, cvA, 0);
    int c = 0;
    for (;;) {
        int mn = ((c + 1) < nch) ? ((c + 1) << 5) : 0;
        LOAD(ckB, cvB, mn);
        PROCESS(ckA, cvA, c);
        if (++c == nch) break;
        mn = ((c + 1) < nch) ? ((c + 1) << 5) : 0;
        LOAD(ckA, cvA, mn);
        PROCESS(ckB, cvB, c);
        if (++c == nch) break;
    }

    // ---- epilogue ----
    auto EPI = [&](int n, float rm, float rs, f32x4* oaccr, bool valid) {
        float r = rs;
        r += __shfl_xor(r, 16);
        r += __shfl_xor(r, 32);
        const float inv = valid ? (1.0f / r) : 0.0f;
        float* op = o + ((size_t)n*QH + (h << 4) + col)*D + (hi << 2);
        #pragma unroll
        for (int dt = 0; dt < 8; ++dt) {
            f32x4 w = oaccr[dt];
            w[0] *= inv; w[1] *= inv; w[2] *= inv; w[3] *= inv;
            *(f32x4*)(op + dt*16) = w;
        }
        if (lane < 16) {
            float lv = valid ? (rm + __logf(r)) : 0.0f;
            lse[((size_t)(h << 4) + col)*N_SEQ + n] = lv;
        }
    };
    EPI(n0r, rmax0, rsum0, oacc0, mcnt0 > 0);
    EPI(n1r, rmax1, rsum1, oacc1, true);
}

extern "C" void kernel_launch(void* const* d_in, const int* in_sizes, int n_in,
                              void* d_out, int out_size, void* d_ws, size_t ws_size,
                              hipStream_t stream)
{
    const float* q      = (const float*)d_in[0];
    const float* k      = (const float*)d_in[1];
    const float* v      = (const float*)d_in[2];
    const float* w_key  = (const float*)d_in[3];
    const float* pe_key = (const float*)d_in[4];
    const float* w_val  = (const float*)d_in[5];
    const float* pe_val = (const float*)d_in[6];

    float* o   = (float*)d_out;                    // (1, 8192, 32, 128)
    float* lse = o + (size_t)N_SEQ * QH * D;       // (1, 32, 8192)
    float* ck  = lse + (size_t)QH * N_SEQ;         // (1, 511, 2, 128)

    unsigned short* ckb  = (unsigned short*)d_ws;  // [KH][512][128] bf16
    unsigned short* cvbT = ckb + (size_t)KH*MP*D;  // [KH][128][512] bf16 (widx-permuted)

    compress_kernel<<<dim3(MP), dim3(256), 0, stream>>>(
        k, v, w_key, pe_key, w_val, pe_val, ck, ckb, cvbT);

    attn_kernel<<<dim3(N_SEQ/8, KH), dim3(256), 0, stream>>>(
        q, ckb, cvbT, o, lse);
}

// Round 5
// 125.497 us; speedup vs baseline: 2.0137x; 1.9434x over previous
//
#include <hip/hip_runtime.h>

#define DI __device__ __forceinline__

using f32x4  = __attribute__((ext_vector_type(4))) float;
using bf16x8 = __attribute__((ext_vector_type(8))) short;
using bf16x4 = __attribute__((ext_vector_type(4))) short;
using u32x2  = __attribute__((ext_vector_type(2))) unsigned int;

DI unsigned short f2bf(float f) {
    unsigned int u = __float_as_uint(f);
    unsigned int r = u + 0x7FFFu + ((u >> 16) & 1u);
    return (unsigned short)(r >> 16);
}

// ---- problem constants ----
constexpr int N_SEQ = 8192;
constexpr int QH    = 32;
constexpr int KH    = 2;
constexpr int D     = 128;
constexpr int M_CMP = 511;
constexpr int MP    = 512;
constexpr int NCH   = 16;              // MP/32 chunks
constexpr int HSTRIDE = NCH * 8 * 64 * 8;   // 65536 elems per head

// ============ Stage 1: block compress ============
// Fragment-major KV layouts so every attn load instruction is one contiguous
// 1KB block (64 lanes x 16B):
//   ckb2[h][c][f = mt*4+kc][lane = hi*16+col][e]  holds ck[m=c*32+mt*16+col][d=kc*32+hi*8+e]
//   cvb2[h][c][dt][lane = hi*16+col][e]           holds cv[m=c*32+(e>>2)*16+hi*4+(e&3)][d=dt*16+col]
__global__ __launch_bounds__(256)
void compress_kernel(const float* __restrict__ kin, const float* __restrict__ vin,
                     const float* __restrict__ w_key, const float* __restrict__ pe_key,
                     const float* __restrict__ w_val, const float* __restrict__ pe_val,
                     float* __restrict__ ck_out,
                     unsigned short* __restrict__ ckb2,
                     unsigned short* __restrict__ cvb2)
{
    const int m  = blockIdx.x;      // 0..511 (511 = zero pad)
    const int t  = threadIdx.x;
    const int hh = t >> 7;
    const int d  = t & 127;
    float acck = 0.f, accv = 0.f;
    if (m < M_CMP) {
        #pragma unroll
        for (int k = 0; k < 32; ++k) {
            float xk = kin[((m*16 + k)*KH + hh)*D + d];
            float xv = vin[((m*16 + k)*KH + hh)*D + d];
            acck += (xk + pe_key[k*D + d]) * w_key[k];
            accv += (xv + pe_val[k*D + d]) * w_val[k];
        }
        acck *= (1.f/32.f);
        accv *= (1.f/32.f);
        ck_out[(m*KH + hh)*D + d] = acck;
    }
    const int c  = m >> 5, ml = m & 31;
    // ck mapping: mt=ml>>4, col=ml&15 ; kc=d>>5, hi=(d>>3)&3, e=d&7
    {
        const int mt = ml >> 4, col = ml & 15;
        const int kc = d >> 5, hi = (d >> 3) & 3, e = d & 7;
        ckb2[(size_t)hh*HSTRIDE + (((c*8 + mt*4 + kc)*64) + hi*16 + col)*8 + e] = f2bf(acck);
    }
    // cv mapping: e = (ml>>4)*4 + (ml&3), hi=(ml>>2)&3 ; dt=d>>4, col=d&15
    {
        const int e  = ((ml >> 4) << 2) + (ml & 3);
        const int hi = (ml >> 2) & 3;
        const int dt = d >> 4, col = d & 15;
        cvb2[(size_t)hh*HSTRIDE + (((c*8 + dt)*64) + hi*16 + col)*8 + e] = f2bf(accv);
    }
}

// ============ Stage 2: attention, coalesced fragment loads ============
// 256 threads = 4 waves. Wave owns rows j and 8191-j (mirror pairing).
// All KV loads are contiguous 1KB-per-instruction from fragment-major buffers.
__global__ __launch_bounds__(256)
void attn_kernel(const float* __restrict__ q,
                 const unsigned short* __restrict__ ckb2,
                 const unsigned short* __restrict__ cvb2,
                 float* __restrict__ o,
                 float* __restrict__ lse)
{
    const int h    = blockIdx.y;
    const int t    = threadIdx.x;
    const int wid  = t >> 6;
    const int lane = t & 63;
    const int col  = lane & 15;
    const int hi   = lane >> 4;
    const int j    = (blockIdx.x << 2) + wid;      // 0..4095

    const int n0r = j;                // short row
    const int n1r = N_SEQ - 1 - j;    // long row (>= 4096)
    const int mcnt0 = (n0r >= 31) ? (((n0r - 31) >> 4) + 1) : 0;
    const int mcnt1 = ((n1r - 31) >> 4) + 1;
    const int nch   = (mcnt1 + 31) >> 5;           // 8..16

    const float sm_scale = 0.08838834764831845f;
    const float NEG_INF  = -__builtin_inff();

    // ---- Q fragments (B-frag of swapped QK^T): B[k=d][col=g] ----
    bf16x8 qf0[4], qf1[4];
    {
        const float* qp0 = q + ((size_t)n0r*QH + (h << 4) + col)*D + (hi << 3);
        const float* qp1 = q + ((size_t)n1r*QH + (h << 4) + col)*D + (hi << 3);
        #pragma unroll
        for (int kc = 0; kc < 4; ++kc) {
            float4 a0 = *(const float4*)(qp0 + kc*32);
            float4 b0 = *(const float4*)(qp0 + kc*32 + 4);
            float4 a1 = *(const float4*)(qp1 + kc*32);
            float4 b1 = *(const float4*)(qp1 + kc*32 + 4);
            bf16x8 f0, f1;
            f0[0]=(short)f2bf(a0.x*sm_scale); f0[1]=(short)f2bf(a0.y*sm_scale);
            f0[2]=(short)f2bf(a0.z*sm_scale); f0[3]=(short)f2bf(a0.w*sm_scale);
            f0[4]=(short)f2bf(b0.x*sm_scale); f0[5]=(short)f2bf(b0.y*sm_scale);
            f0[6]=(short)f2bf(b0.z*sm_scale); f0[7]=(short)f2bf(b0.w*sm_scale);
            f1[0]=(short)f2bf(a1.x*sm_scale); f1[1]=(short)f2bf(a1.y*sm_scale);
            f1[2]=(short)f2bf(a1.z*sm_scale); f1[3]=(short)f2bf(a1.w*sm_scale);
            f1[4]=(short)f2bf(b1.x*sm_scale); f1[5]=(short)f2bf(b1.y*sm_scale);
            f1[6]=(short)f2bf(b1.z*sm_scale); f1[7]=(short)f2bf(b1.w*sm_scale);
            qf0[kc] = f0; qf1[kc] = f1;
        }
    }

    f32x4 oacc0[8], oacc1[8];
    #pragma unroll
    for (int dt = 0; dt < 8; ++dt) {
        oacc0[dt] = (f32x4){0.f,0.f,0.f,0.f};
        oacc1[dt] = (f32x4){0.f,0.f,0.f,0.f};
    }
    float rmax0 = -3e38f, rmax1 = -3e38f, rsum0 = 0.f, rsum1 = 0.f;

    // per-lane fragment bases: element offset = (c*8 + f)*512 + lane*8
    const unsigned short* ckh = ckb2 + (size_t)h*HSTRIDE + (size_t)lane*8;
    const unsigned short* cvh = cvb2 + (size_t)h*HSTRIDE + (size_t)lane*8;

    bf16x8 ckA[8], cvA[8], ckB[8], cvB[8];

    auto LOAD = [&](bf16x8* ckr, bf16x8* cvr, int c) {
        const size_t base = (size_t)c * 8 * 512;
        #pragma unroll
        for (int f = 0; f < 8; ++f)
            ckr[f] = *(const bf16x8*)(ckh + base + f*512);
        #pragma unroll
        for (int dt = 0; dt < 8; ++dt)
            cvr[dt] = *(const bf16x8*)(cvh + base + dt*512);
    };

    // softmax for one row: sa = mt0 scores, sb = mt1 scores
    auto SMAX = [&](f32x4 sa, f32x4 sb, int lim, float& rm, float& rs,
                    f32x4* oaccr, unsigned int* pw) {
        const int mb = hi << 2;
        float sv[8];
        #pragma unroll
        for (int jj = 0; jj < 4; ++jj) {
            sv[jj]     = (mb + jj      < lim) ? sa[jj] : NEG_INF;
            sv[4 + jj] = (mb + jj + 16 < lim) ? sb[jj] : NEG_INF;
        }
        float pm = fmaxf(fmaxf(fmaxf(sv[0],sv[1]), fmaxf(sv[2],sv[3])),
                         fmaxf(fmaxf(sv[4],sv[5]), fmaxf(sv[6],sv[7])));
        if (!__all(pm <= rm + 8.0f)) {
            float tm = pm;
            tm = fmaxf(tm, __shfl_xor(tm, 16));
            tm = fmaxf(tm, __shfl_xor(tm, 32));
            float nm = fmaxf(rm, tm);
            float sc = __expf(rm - nm);
            rs *= sc;
            #pragma unroll
            for (int dt = 0; dt < 8; ++dt) {
                oaccr[dt][0] *= sc; oaccr[dt][1] *= sc;
                oaccr[dt][2] *= sc; oaccr[dt][3] *= sc;
            }
            rm = nm;
        }
        float p[8], lsum = 0.f;
        #pragma unroll
        for (int i = 0; i < 8; ++i) { p[i] = __expf(sv[i] - rm); lsum += p[i]; }
        rs += lsum;
        asm("v_cvt_pk_bf16_f32 %0, %1, %2" : "=v"(pw[0]) : "v"(p[0]), "v"(p[1]));
        asm("v_cvt_pk_bf16_f32 %0, %1, %2" : "=v"(pw[1]) : "v"(p[2]), "v"(p[3]));
        asm("v_cvt_pk_bf16_f32 %0, %1, %2" : "=v"(pw[2]) : "v"(p[4]), "v"(p[5]));
        asm("v_cvt_pk_bf16_f32 %0, %1, %2" : "=v"(pw[3]) : "v"(p[6]), "v"(p[7]));
    };

    auto PROCESS = [&](const bf16x8* ckr, const bf16x8* cvr, int c) {
        const int m0   = c << 5;
        const bool act0 = (m0 < mcnt0);          // wave-uniform

        // ---- QK^T long row (always active) ----
        f32x4 s10 = (f32x4){0,0,0,0}, s11 = (f32x4){0,0,0,0};
        #pragma unroll
        for (int kc = 0; kc < 4; ++kc) {
            s10 = __builtin_amdgcn_mfma_f32_16x16x32_bf16(ckr[kc],     qf1[kc], s10, 0, 0, 0);
            s11 = __builtin_amdgcn_mfma_f32_16x16x32_bf16(ckr[4 + kc], qf1[kc], s11, 0, 0, 0);
        }
        unsigned int pw1[4];
        SMAX(s10, s11, mcnt1 - m0, rmax1, rsum1, oacc1, pw1);

        unsigned int pw0[4];
        if (act0) {
            f32x4 s00 = (f32x4){0,0,0,0}, s01 = (f32x4){0,0,0,0};
            #pragma unroll
            for (int kc = 0; kc < 4; ++kc) {
                s00 = __builtin_amdgcn_mfma_f32_16x16x32_bf16(ckr[kc],     qf0[kc], s00, 0, 0, 0);
                s01 = __builtin_amdgcn_mfma_f32_16x16x32_bf16(ckr[4 + kc], qf0[kc], s01, 0, 0, 0);
            }
            SMAX(s00, s01, mcnt0 - m0, rmax0, rsum0, oacc0, pw0);
        }

        // ---- PV long row ----
        {
            u32x2 b0 = {pw1[0], pw1[1]}, b1 = {pw1[2], pw1[3]};
            #pragma unroll
            for (int dt = 0; dt < 8; ++dt) {
                bf16x4 a0 = __builtin_shufflevector(cvr[dt], cvr[dt], 0,1,2,3);
                bf16x4 a1 = __builtin_shufflevector(cvr[dt], cvr[dt], 4,5,6,7);
                asm("v_mfma_f32_16x16x16_bf16 %0, %1, %2, %0"
                    : "+v"(oacc1[dt]) : "v"(a0), "v"(b0));
                asm("v_mfma_f32_16x16x16_bf16 %0, %1, %2, %0"
                    : "+v"(oacc1[dt]) : "v"(a1), "v"(b1));
            }
        }
        // ---- PV short row ----
        if (act0) {
            u32x2 b0 = {pw0[0], pw0[1]}, b1 = {pw0[2], pw0[3]};
            #pragma unroll
            for (int dt = 0; dt < 8; ++dt) {
                bf16x4 a0 = __builtin_shufflevector(cvr[dt], cvr[dt], 0,1,2,3);
                bf16x4 a1 = __builtin_shufflevector(cvr[dt], cvr[dt], 4,5,6,7);
                asm("v_mfma_f32_16x16x16_bf16 %0, %1, %2, %0"
                    : "+v"(oacc0[dt]) : "v"(a0), "v"(b0));
                asm("v_mfma_f32_16x16x16_bf16 %0, %1, %2, %0"
                    : "+v"(oacc0[dt]) : "v"(a1), "v"(b1));
            }
        }
    };

    // ---- software-pipelined chunk loop (A/B register double-buffer) ----
    LOAD(ckA, cvA, 0);
    int c = 0;
    for (;;) {
        int cn = ((c + 1) < nch) ? (c + 1) : 0;
        LOAD(ckB, cvB, cn);
        PROCESS(ckA, cvA, c);
        if (++c == nch) break;
        cn = ((c + 1) < nch) ? (c + 1) : 0;
        LOAD(ckA, cvA, cn);
        PROCESS(ckB, cvB, c);
        if (++c == nch) break;
    }

    // ---- epilogue ----
    auto EPI = [&](int n, float rm, float rs, f32x4* oaccr, bool valid) {
        float r = rs;
        r += __shfl_xor(r, 16);
        r += __shfl_xor(r, 32);
        const float inv = valid ? (1.0f / r) : 0.0f;
        float* op = o + ((size_t)n*QH + (h << 4) + col)*D + (hi << 2);
        #pragma unroll
        for (int dt = 0; dt < 8; ++dt) {
            f32x4 w = oaccr[dt];
            w[0] *= inv; w[1] *= inv; w[2] *= inv; w[3] *= inv;
            *(f32x4*)(op + dt*16) = w;
        }
        if (lane < 16) {
            float lv = valid ? (rm + __logf(r)) : 0.0f;
            lse[((size_t)(h << 4) + col)*N_SEQ + n] = lv;
        }
    };
    EPI(n0r, rmax0, rsum0, oacc0, mcnt0 > 0);
    EPI(n1r, rmax1, rsum1, oacc1, true);
}

extern "C" void kernel_launch(void* const* d_in, const int* in_sizes, int n_in,
                              void* d_out, int out_size, void* d_ws, size_t ws_size,
                              hipStream_t stream)
{
    const float* q      = (const float*)d_in[0];
    const float* k      = (const float*)d_in[1];
    const float* v      = (const float*)d_in[2];
    const float* w_key  = (const float*)d_in[3];
    const float* pe_key = (const float*)d_in[4];
    const float* w_val  = (const float*)d_in[5];
    const float* pe_val = (const float*)d_in[6];

    float* o   = (float*)d_out;                    // (1, 8192, 32, 128)
    float* lse = o + (size_t)N_SEQ * QH * D;       // (1, 32, 8192)
    float* ck  = lse + (size_t)QH * N_SEQ;         // (1, 511, 2, 128)

    unsigned short* ckb2 = (unsigned short*)d_ws;      // [KH][HSTRIDE] bf16, frag-major
    unsigned short* cvb2 = ckb2 + (size_t)KH*HSTRIDE;  // [KH][HSTRIDE] bf16, frag-major

    compress_kernel<<<dim3(MP), dim3(256), 0, stream>>>(
        k, v, w_key, pe_key, w_val, pe_val, ck, ckb2, cvb2);

    attn_kernel<<<dim3(N_SEQ/8, KH), dim3(256), 0, stream>>>(
        q, ckb2, cvb2, o, lse);
}

// Round 6
// 102.117 us; speedup vs baseline: 2.4748x; 1.2290x over previous
//
#include <hip/hip_runtime.h>

#define DI __device__ __forceinline__

using f32x4  = __attribute__((ext_vector_type(4))) float;
using bf16x8 = __attribute__((ext_vector_type(8))) short;
using bf16x4 = __attribute__((ext_vector_type(4))) short;
using u32x2  = __attribute__((ext_vector_type(2))) unsigned int;

DI unsigned short f2bf(float f) {
    unsigned int u = __float_as_uint(f);
    unsigned int r = u + 0x7FFFu + ((u >> 16) & 1u);
    return (unsigned short)(r >> 16);
}

// async global->LDS, 16B per lane (wave-uniform LDS base + lane*16)
DI void gload_lds16(const void* g, void* l) {
    __builtin_amdgcn_global_load_lds(
        (const __attribute__((address_space(1))) void*)(unsigned long long)g,
        (__attribute__((address_space(3))) void*)(unsigned int)(unsigned long long)l,
        16, 0, 0);
}

// ---- problem constants ----
constexpr int N_SEQ = 8192;
constexpr int QH    = 32;
constexpr int KH    = 2;
constexpr int D     = 128;
constexpr int M_CMP = 511;
constexpr int MP    = 512;
constexpr int NCH   = 16;                       // 512/32 chunks
constexpr int CHUNK_ELEMS = 16 * 64 * 8;        // 16 frags x 64 lanes x 8 = 16KB
constexpr int HSTRIDE = NCH * CHUNK_ELEMS;      // per-head elems

// ============ Stage 1: block compress ============
// Unified fragment-major KV: kvb[h][c][fi][lane][8], fi 0-7 = ck frags
// (fi = mt*4+kc), fi 8-15 = cv frags (fi = 8+dt). One chunk = contiguous 16KB.
__global__ __launch_bounds__(256)
void compress_kernel(const float* __restrict__ kin, const float* __restrict__ vin,
                     const float* __restrict__ w_key, const float* __restrict__ pe_key,
                     const float* __restrict__ w_val, const float* __restrict__ pe_val,
                     float* __restrict__ ck_out,
                     unsigned short* __restrict__ kvb)
{
    const int m  = blockIdx.x;      // 0..511 (511 = zero pad)
    const int t  = threadIdx.x;
    const int hh = t >> 7;
    const int d  = t & 127;
    float acck = 0.f, accv = 0.f;
    if (m < M_CMP) {
        #pragma unroll
        for (int k = 0; k < 32; ++k) {
            float xk = kin[((m*16 + k)*KH + hh)*D + d];
            float xv = vin[((m*16 + k)*KH + hh)*D + d];
            acck += (xk + pe_key[k*D + d]) * w_key[k];
            accv += (xv + pe_val[k*D + d]) * w_val[k];
        }
        acck *= (1.f/32.f);
        accv *= (1.f/32.f);
        ck_out[(m*KH + hh)*D + d] = acck;
    }
    const int c = m >> 5, ml = m & 31;
    // ck: frag fi = mt*4+kc holds ck[m=c*32+mt*16+col][d=kc*32+hix*8+e]
    {
        const int mt = ml >> 4, colx = ml & 15;
        const int kc = d >> 5, hix = (d >> 3) & 3, e = d & 7;
        kvb[(size_t)hh*HSTRIDE + (((c*16 + mt*4 + kc)*64) + hix*16 + colx)*8 + e] = f2bf(acck);
    }
    // cv: frag fi = 8+dt holds cv[m=c*32+(e>>2)*16+hix*4+(e&3)][d=dt*16+colx]
    {
        const int e   = ((ml >> 4) << 2) + (ml & 3);
        const int hix = (ml >> 2) & 3;
        const int dt  = d >> 4, colx = d & 15;
        kvb[(size_t)hh*HSTRIDE + (((c*16 + 8 + dt)*64) + hix*16 + colx)*8 + e] = f2bf(accv);
    }
}

// ============ Stage 2: LDS-shared, async-staged attention ============
// 256 threads = 4 waves. Wave owns rows j and 8191-j. Per chunk: block stages
// 16KB to LDS via global_load_lds (issued before compute, drained by the
// barrier), all waves read fragments via conflict-free ds_read_b128.
__global__ __launch_bounds__(256)
void attn_kernel(const float* __restrict__ q,
                 const unsigned short* __restrict__ kvb,
                 float* __restrict__ o,
                 float* __restrict__ lse)
{
    __shared__ __align__(16) unsigned short lds[2][16][64][8];   // 2 x 16KB

    const int h    = blockIdx.y;
    const int t    = threadIdx.x;
    const int wid  = t >> 6;
    const int lane = t & 63;
    const int col  = lane & 15;
    const int hi   = lane >> 4;
    const int j    = (blockIdx.x << 2) + wid;      // 0..4095

    const int n0r = j;                // short row
    const int n1r = N_SEQ - 1 - j;    // long row (>= 4096)
    const int mcnt0 = (n0r >= 31) ? (((n0r - 31) >> 4) + 1) : 0;
    const int mcnt1 = ((n1r - 31) >> 4) + 1;
    // block-uniform chunk count (from the block's longest row)
    const int n1max = N_SEQ - 1 - (blockIdx.x << 2);
    const int nchb  = (((((n1max - 31) >> 4) + 1) + 31) >> 5);   // 8..16

    const float sm_scale = 0.08838834764831845f;
    const float NEG_INF  = -__builtin_inff();

    // ---- Q fragments (B-frag of swapped QK^T): B[k=d][col=g] ----
    bf16x8 qf0[4], qf1[4];
    {
        const float* qp0 = q + ((size_t)n0r*QH + (h << 4) + col)*D + (hi << 3);
        const float* qp1 = q + ((size_t)n1r*QH + (h << 4) + col)*D + (hi << 3);
        #pragma unroll
        for (int kc = 0; kc < 4; ++kc) {
            float4 a0 = *(const float4*)(qp0 + kc*32);
            float4 b0 = *(const float4*)(qp0 + kc*32 + 4);
            float4 a1 = *(const float4*)(qp1 + kc*32);
            float4 b1 = *(const float4*)(qp1 + kc*32 + 4);
            bf16x8 f0, f1;
            f0[0]=(short)f2bf(a0.x*sm_scale); f0[1]=(short)f2bf(a0.y*sm_scale);
            f0[2]=(short)f2bf(a0.z*sm_scale); f0[3]=(short)f2bf(a0.w*sm_scale);
            f0[4]=(short)f2bf(b0.x*sm_scale); f0[5]=(short)f2bf(b0.y*sm_scale);
            f0[6]=(short)f2bf(b0.z*sm_scale); f0[7]=(short)f2bf(b0.w*sm_scale);
            f1[0]=(short)f2bf(a1.x*sm_scale); f1[1]=(short)f2bf(a1.y*sm_scale);
            f1[2]=(short)f2bf(a1.z*sm_scale); f1[3]=(short)f2bf(a1.w*sm_scale);
            f1[4]=(short)f2bf(b1.x*sm_scale); f1[5]=(short)f2bf(b1.y*sm_scale);
            f1[6]=(short)f2bf(b1.z*sm_scale); f1[7]=(short)f2bf(b1.w*sm_scale);
            qf0[kc] = f0; qf1[kc] = f1;
        }
    }

    f32x4 oacc0[8], oacc1[8];
    #pragma unroll
    for (int dt = 0; dt < 8; ++dt) {
        oacc0[dt] = (f32x4){0.f,0.f,0.f,0.f};
        oacc1[dt] = (f32x4){0.f,0.f,0.f,0.f};
    }
    float rmax0 = -3e38f, rmax1 = -3e38f, rsum0 = 0.f, rsum1 = 0.f;

    const unsigned short* kvh = kvb + (size_t)h*HSTRIDE;

    auto STAGE = [&](int buf, int c) {
        const unsigned short* gp = kvh + ((size_t)(c*16 + (wid << 2))*64 + lane)*8;
        #pragma unroll
        for (int p = 0; p < 4; ++p)
            gload_lds16(gp + p*512, &lds[buf][(wid << 2) + p][lane][0]);
    };

    auto SMAX = [&](f32x4 sa, f32x4 sb, int lim, float& rm, float& rs,
                    f32x4* oaccr, unsigned int* pw) {
        float sv[8];
        if (lim < 32) {                      // boundary chunk only
            const int mb = hi << 2;
            #pragma unroll
            for (int jj = 0; jj < 4; ++jj) {
                sv[jj]     = (mb + jj      < lim) ? sa[jj] : NEG_INF;
                sv[4 + jj] = (mb + jj + 16 < lim) ? sb[jj] : NEG_INF;
            }
        } else {
            #pragma unroll
            for (int jj = 0; jj < 4; ++jj) { sv[jj] = sa[jj]; sv[4 + jj] = sb[jj]; }
        }
        float pm = fmaxf(fmaxf(fmaxf(sv[0],sv[1]), fmaxf(sv[2],sv[3])),
                         fmaxf(fmaxf(sv[4],sv[5]), fmaxf(sv[6],sv[7])));
        if (!__all(pm <= rm + 8.0f)) {
            float tm = pm;
            tm = fmaxf(tm, __shfl_xor(tm, 16));
            tm = fmaxf(tm, __shfl_xor(tm, 32));
            float nm = fmaxf(rm, tm);
            float sc = __expf(rm - nm);
            rs *= sc;
            #pragma unroll
            for (int dt = 0; dt < 8; ++dt) {
                oaccr[dt][0] *= sc; oaccr[dt][1] *= sc;
                oaccr[dt][2] *= sc; oaccr[dt][3] *= sc;
            }
            rm = nm;
        }
        float p[8], lsum = 0.f;
        #pragma unroll
        for (int i = 0; i < 8; ++i) { p[i] = __expf(sv[i] - rm); lsum += p[i]; }
        rs += lsum;
        asm("v_cvt_pk_bf16_f32 %0, %1, %2" : "=v"(pw[0]) : "v"(p[0]), "v"(p[1]));
        asm("v_cvt_pk_bf16_f32 %0, %1, %2" : "=v"(pw[1]) : "v"(p[2]), "v"(p[3]));
        asm("v_cvt_pk_bf16_f32 %0, %1, %2" : "=v"(pw[2]) : "v"(p[4]), "v"(p[5]));
        asm("v_cvt_pk_bf16_f32 %0, %1, %2" : "=v"(pw[3]) : "v"(p[6]), "v"(p[7]));
    };

    // ---- main chunk loop: 1 barrier per chunk, stage issued before compute ----
    STAGE(0, 0);
    __syncthreads();                 // drains vmcnt(0): buf0 ready

    for (int c = 0; c < nchb; ++c) {
        if (c + 1 < nchb) STAGE((c + 1) & 1, c + 1);

        const int m0 = c << 5;
        const bool a1 = (m0 < mcnt1);
        const bool a0 = (m0 < mcnt0);
        const unsigned short (*L)[64][8] = lds[c & 1];

        // ---- QK^T (ck frags shared by both rows) ----
        f32x4 s10 = (f32x4){0,0,0,0}, s11 = (f32x4){0,0,0,0};
        f32x4 s00 = (f32x4){0,0,0,0}, s01 = (f32x4){0,0,0,0};
        #pragma unroll
        for (int kc = 0; kc < 4; ++kc) {
            bf16x8 ca = *(const bf16x8*)&L[kc][lane][0];
            bf16x8 cb = *(const bf16x8*)&L[4 + kc][lane][0];
            s10 = __builtin_amdgcn_mfma_f32_16x16x32_bf16(ca, qf1[kc], s10, 0, 0, 0);
            s11 = __builtin_amdgcn_mfma_f32_16x16x32_bf16(cb, qf1[kc], s11, 0, 0, 0);
            if (a0) {
                s00 = __builtin_amdgcn_mfma_f32_16x16x32_bf16(ca, qf0[kc], s00, 0, 0, 0);
                s01 = __builtin_amdgcn_mfma_f32_16x16x32_bf16(cb, qf0[kc], s01, 0, 0, 0);
            }
        }
        unsigned int pw1[4], pw0[4];
        if (a1) SMAX(s10, s11, mcnt1 - m0, rmax1, rsum1, oacc1, pw1);
        if (a0) SMAX(s00, s01, mcnt0 - m0, rmax0, rsum0, oacc0, pw0);

        // ---- PV (cv frags shared by both rows) ----
        #pragma unroll
        for (int dt = 0; dt < 8; ++dt) {
            bf16x8 cv = *(const bf16x8*)&L[8 + dt][lane][0];
            bf16x4 va = __builtin_shufflevector(cv, cv, 0,1,2,3);
            bf16x4 vb = __builtin_shufflevector(cv, cv, 4,5,6,7);
            if (a1) {
                u32x2 b0 = {pw1[0], pw1[1]}, b1 = {pw1[2], pw1[3]};
                asm("v_mfma_f32_16x16x16_bf16 %0, %1, %2, %0"
                    : "+v"(oacc1[dt]) : "v"(va), "v"(b0));
                asm("v_mfma_f32_16x16x16_bf16 %0, %1, %2, %0"
                    : "+v"(oacc1[dt]) : "v"(vb), "v"(b1));
            }
            if (a0) {
                u32x2 b0 = {pw0[0], pw0[1]}, b1 = {pw0[2], pw0[3]};
                asm("v_mfma_f32_16x16x16_bf16 %0, %1, %2, %0"
                    : "+v"(oacc0[dt]) : "v"(va), "v"(b0));
                asm("v_mfma_f32_16x16x16_bf16 %0, %1, %2, %0"
                    : "+v"(oacc0[dt]) : "v"(vb), "v"(b1));
            }
        }

        __syncthreads();   // stage of buf[(c+1)&1] drained; reads of buf[c&1] done
    }

    // ---- epilogue ----
    auto EPI = [&](int n, float rm, float rs, f32x4* oaccr, bool valid) {
        float r = rs;
        r += __shfl_xor(r, 16);
        r += __shfl_xor(r, 32);
        const float inv = valid ? (1.0f / r) : 0.0f;
        float* op = o + ((size_t)n*QH + (h << 4) + col)*D + (hi << 2);
        #pragma unroll
        for (int dt = 0; dt < 8; ++dt) {
            f32x4 w = oaccr[dt];
            w[0] *= inv; w[1] *= inv; w[2] *= inv; w[3] *= inv;
            *(f32x4*)(op + dt*16) = w;
        }
        if (lane < 16) {
            float lv = valid ? (rm + __logf(r)) : 0.0f;
            lse[((size_t)(h << 4) + col)*N_SEQ + n] = lv;
        }
    };
    EPI(n0r, rmax0, rsum0, oacc0, mcnt0 > 0);
    EPI(n1r, rmax1, rsum1, oacc1, true);
}

extern "C" void kernel_launch(void* const* d_in, const int* in_sizes, int n_in,
                              void* d_out, int out_size, void* d_ws, size_t ws_size,
                              hipStream_t stream)
{
    const float* q      = (const float*)d_in[0];
    const float* k      = (const float*)d_in[1];
    const float* v      = (const float*)d_in[2];
    const float* w_key  = (const float*)d_in[3];
    const float* pe_key = (const float*)d_in[4];
    const float* w_val  = (const float*)d_in[5];
    const float* pe_val = (const float*)d_in[6];

    float* o   = (float*)d_out;                    // (1, 8192, 32, 128)
    float* lse = o + (size_t)N_SEQ * QH * D;       // (1, 32, 8192)
    float* ck  = lse + (size_t)QH * N_SEQ;         // (1, 511, 2, 128)

    unsigned short* kvb = (unsigned short*)d_ws;   // [KH][NCH][16][64][8] bf16

    compress_kernel<<<dim3(MP), dim3(256), 0, stream>>>(
        k, v, w_key, pe_key, w_val, pe_val, ck, kvb);

    attn_kernel<<<dim3(N_SEQ/8, KH), dim3(256), 0, stream>>>(
        q, kvb, o, lse);
}